// Round 5
// baseline (591.174 us; speedup 1.0000x reference)
//
#include <hip/hip_runtime.h>

typedef unsigned short u16;
typedef unsigned int u32;
typedef __attribute__((ext_vector_type(8))) short short8;
typedef __attribute__((ext_vector_type(4))) short bf16x4;
typedef __attribute__((ext_vector_type(4))) float f32x4;

#define M_ROWS 32768
#define MFMA16 __builtin_amdgcn_mfma_f32_16x16x32_bf16

__device__ __forceinline__ float bf2f(u16 u) {
  u32 x = ((u32)u) << 16;
  return __builtin_bit_cast(float, x);
}
__device__ __forceinline__ u16 f2bf(float f) {
  u32 x = __builtin_bit_cast(u32, f);
  x += 0x7fffu + ((x >> 16) & 1u);
  return (u16)(x >> 16);
}
// load 8 fp32 from p, RNE-round to one short8
__device__ __forceinline__ short8 ld8f(const float* p) {
  f32x4 x0 = *(const f32x4*)p;
  f32x4 x1 = *(const f32x4*)(p + 4);
  short8 s;
#pragma unroll
  for (int i = 0; i < 4; ++i) { s[i] = (short)f2bf(x0[i]); s[4 + i] = (short)f2bf(x1[i]); }
  return s;
}

// async global->LDS, 16B per lane, LDS dest = wave-uniform base + lane*16
__device__ __forceinline__ void lds16(u16* l, const u16* g) {
  __builtin_amdgcn_global_load_lds(
      (const __attribute__((address_space(1))) void*)g,
      (__attribute__((address_space(3))) void*)l, 16, 0, 0);
}

// ---------------- input pack: fp32 -> bf16 (+ ctx gather) -----------------------
__global__ __launch_bounds__(256) void pack(
    const float* gvec, const float* xnode, const float* znode,
    const float* src, const float* atom1h, const int* bidx,
    u16* gvecB, u16* xnodeB, u16* znodeB, u16* ctxB, u16* a1hB) {
  int id = blockIdx.x * 256 + threadIdx.x;  // one short8 chunk each
  const int NG = M_ROWS * 512 / 8;          // 2097152
  if (id < NG) { ((short8*)gvecB)[id] = ld8f(gvec + (size_t)id * 8); return; }
  id -= NG;
  if (id < NG) { ((short8*)xnodeB)[id] = ld8f(xnode + (size_t)id * 8); return; }
  id -= NG;
  if (id < NG) { ((short8*)znodeB)[id] = ld8f(znode + (size_t)id * 8); return; }
  id -= NG;
  const int NC = M_ROWS * 128 / 8;          // 524288
  if (id < NC) {
    const int m = id >> 4, c8 = (id & 15) * 8;
    ((short8*)ctxB)[id] = ld8f(src + (size_t)bidx[m] * 128 + c8);
    return;
  }
  id -= NC;
  const int NA = M_ROWS * 64 / 8;           // 262144
  if (id < NA) { ((short8*)a1hB)[id] = ld8f(atom1h + (size_t)id * 8); return; }
}

// ---- 256x256 GEMM, quad-buffered 32-K sub-tiles, counted vmcnt (T2+T4+T5) ------
// out = relu(A @ B^T + bias [+ tail rank-4]) in bf16
struct SegB { const u16* ptr; int ld; int kstart; };
struct GArgs {
  SegB seg[4];
  int nseg;
  const u16* bt;       // B^T [N][K] bf16
  const float* biasf;  // [N] fp32
  u16* out;            // [M][N] relu'd bf16
  int K;
  int N;
  const float* tail_w; // fp32 wbond_w rows 512..515 (ld 512) or null
  const float* tail_x; // fp32 bond_onehot [M][4] or null
};

__global__ __launch_bounds__(512) void gemm256(GArgs a) {
  // 4 sub-tile buffers: 256 rows x 32 cols bf16 = 16 KB each, A + B = 128 KB
  __shared__ __align__(16) u16 Asub[4][8192];
  __shared__ __align__(16) u16 Bsub[4][8192];
  const int tid = threadIdx.x;
  // bijective XCD-chunked swizzle (nwg % 8 == 0 in all launches)
  const int nwg = gridDim.x * gridDim.y;
  const int orig = blockIdx.y * gridDim.x + blockIdx.x;
  const int swz = (orig & 7) * (nwg >> 3) + (orig >> 3);
  const int bn = swz % gridDim.x, bm = swz / gridDim.x;
  const int wave = tid >> 6, lane = tid & 63;
  const int wm = wave >> 2, wn = wave & 3;   // 2M x 4N wave grid
  const int lm = lane & 15, lq = lane >> 4;
  // staging: thread covers (row = h*128 + srow2, 16B slot = tid&3)
  const int srow2 = tid >> 2;                             // 0..127
  const int scol = ((tid & 3) ^ ((srow2 >> 1) & 3)) * 8;  // pre-swizzled src col
  // frag read: row base multiple of 16 -> f(row) = (lm>>1)&3
  const int cxe = (lq ^ ((lm >> 1) & 3)) * 8;             // swizzled col elems
  const int K = a.K;
  const int ns = K >> 5;                                  // # 32-K sub-tiles
  const u16* bpan = a.bt + (size_t)(bn * 256) * K;
  f32x4 acc[8][4] = {};

  // prologue: stage sub-tiles 0,1,2 (12 loads/thread, FIFO order)
#pragma unroll
  for (int s = 0; s < 3; ++s) {
    const int kb = s * 32;
    int si = a.nseg - 1;
    while (si > 0 && kb < a.seg[si].kstart) --si;
    const int ald = a.seg[si].ld;
    const u16* ap = a.seg[si].ptr + (size_t)(bm * 256) * ald + (kb - a.seg[si].kstart) + scol;
    const u16* bp = bpan + kb + scol;
    u16* Aw = Asub[s]; u16* Bw = Bsub[s];
    lds16(Aw + tid * 8,        ap + (size_t)srow2 * ald);
    lds16(Aw + 4096 + tid * 8, ap + (size_t)(128 + srow2) * ald);
    lds16(Bw + tid * 8,        bp + (size_t)srow2 * K);
    lds16(Bw + 4096 + tid * 8, bp + (size_t)(128 + srow2) * K);
  }

  for (int s = 0; s < ns; ++s) {
    // counted wait: sub-tile s's 4 loads are the oldest; keep s+1,s+2 in flight
    const int left = ns - 1 - s;
    if (left >= 2)      asm volatile("s_waitcnt vmcnt(8)" ::: "memory");
    else if (left == 1) asm volatile("s_waitcnt vmcnt(4)" ::: "memory");
    else                asm volatile("s_waitcnt vmcnt(0)" ::: "memory");
    __builtin_amdgcn_s_barrier();   // all waves' s-loads landed; all s-1 reads done
    __builtin_amdgcn_sched_barrier(0);
    // stage sub-tile s+3 into buffer (s+3)&3 == (s-1)&3 (freed by the barrier)
    if (s + 3 < ns) {
      const int kb2 = (s + 3) * 32;
      int si = a.nseg - 1;
      while (si > 0 && kb2 < a.seg[si].kstart) --si;
      const int ald = a.seg[si].ld;
      const u16* ap = a.seg[si].ptr + (size_t)(bm * 256) * ald + (kb2 - a.seg[si].kstart) + scol;
      const u16* bp = bpan + kb2 + scol;
      u16* Aw = Asub[(s + 3) & 3]; u16* Bw = Bsub[(s + 3) & 3];
      lds16(Aw + tid * 8,        ap + (size_t)srow2 * ald);
      lds16(Aw + 4096 + tid * 8, ap + (size_t)(128 + srow2) * ald);
      lds16(Bw + tid * 8,        bp + (size_t)srow2 * K);
      lds16(Bw + 4096 + tid * 8, bp + (size_t)(128 + srow2) * K);
    }
    // compute sub-tile s
    const u16* Ar = Asub[s & 3];
    const u16* Br = Bsub[s & 3];
    short8 af[8], bfv[4];
#pragma unroll
    for (int m = 0; m < 8; ++m)
      af[m] = *(const short8*)&Ar[(wm * 128 + m * 16 + lm) * 32 + cxe];
#pragma unroll
    for (int n = 0; n < 4; ++n)
      bfv[n] = *(const short8*)&Br[(wn * 64 + n * 16 + lm) * 32 + cxe];
    __builtin_amdgcn_s_setprio(1);
#pragma unroll
    for (int m = 0; m < 8; ++m)
#pragma unroll
      for (int n = 0; n < 4; ++n)
        acc[m][n] = MFMA16(af[m], bfv[n], acc[m][n], 0, 0, 0);
    __builtin_amdgcn_s_setprio(0);
  }

  // ---- epilogue: bias [+rank-4 tail] + relu + bf16 store ----
  const int gc0 = bn * 256 + wn * 64 + lm;
  float biasv[4], tw[4][4];
#pragma unroll
  for (int j = 0; j < 4; ++j) {
    biasv[j] = a.biasf[gc0 + j * 16];
    if (a.tail_w) {
#pragma unroll
      for (int o = 0; o < 4; ++o) tw[j][o] = a.tail_w[o * 512 + gc0 + j * 16];
    }
  }
#pragma unroll
  for (int i = 0; i < 8; ++i) {
#pragma unroll
    for (int r = 0; r < 4; ++r) {
      const int gr = bm * 256 + wm * 128 + i * 16 + lq * 4 + r;
      float tx0 = 0.f, tx1 = 0.f, tx2 = 0.f, tx3 = 0.f;
      if (a.tail_w) {
        f32x4 t = *(const f32x4*)&a.tail_x[gr * 4];
        tx0 = t[0]; tx1 = t[1]; tx2 = t[2]; tx3 = t[3];
      }
#pragma unroll
      for (int j = 0; j < 4; ++j) {
        float v = acc[i][j][r] + biasv[j];
        if (a.tail_w) v += tx0 * tw[j][0] + tx1 * tw[j][1] + tx2 * tw[j][2] + tx3 * tw[j][3];
        v = v > 0.f ? v : 0.f;
        a.out[(size_t)gr * a.N + gc0 + j * 16] = f2bf(v);
      }
    }
  }
}

// ---------------- topo + atom heads from materialized h1 [M][1024] --------------
struct THArgs {
  const u16* h1;      // [M][1024] relu'd bf16 (cols 0..511 topo, 512..1023 atom)
  const float* tw2;   // topo_w2 [512] fp32
  const float* tb2;   // topo_b2 [1]
  const u16* aw2t;    // AT2 [64][512] bf16
  const float* ab2;   // atom_b2 [64]
  float* out;         // [M][69] fp32
};

__global__ __launch_bounds__(256) void ta_heads(THArgs a) {
  __shared__ u16 hbuf[128 * 136];
  const int tid = threadIdx.x;
  const int half = blockIdx.x, bm = blockIdx.y;  // half: 0=topo, 1=atom
  const int wave = tid >> 6, lane = tid & 63;
  const int lm = lane & 15, lq = lane >> 4;

  float topo_acc = 0.f;
  f32x4 acc2[2][4] = {};

  for (int t = 0; t < 4; ++t) {
    // stage h1[bm*128 ..][half*512 + t*128 ..] -> hbuf[128][136] (padded)
#pragma unroll
    for (int it = 0; it < 8; ++it) {
      const int id = it * 256 + tid;
      const int row = id >> 4, c8 = (id & 15) * 8;
      short8 v = *(const short8*)(a.h1 + (size_t)(bm * 128 + row) * 1024 + half * 512 + t * 128 + c8);
      *(short8*)&hbuf[row * 136 + c8] = v;
    }
    __syncthreads();

    if (half == 0) {
      const int srw = tid >> 1, sh = tid & 1;
      const u16* hrow = &hbuf[srw * 136 + sh * 64];
      float s = 0.f;
      for (int cc = 0; cc < 64; ++cc)
        s += bf2f(hrow[cc]) * a.tw2[t * 128 + sh * 64 + cc];
      topo_acc += s;
    } else {
#pragma unroll
      for (int ks2 = 0; ks2 < 4; ++ks2) {
#pragma unroll
        for (int i2 = 0; i2 < 2; ++i2) {
          const short8 af2 = *(const short8*)&hbuf[(wave * 32 + i2 * 16 + lm) * 136 + ks2 * 32 + lq * 8];
#pragma unroll
          for (int j2 = 0; j2 < 4; ++j2) {
            const short8 bf2v = *(const short8*)&a.aw2t[(size_t)(j2 * 16 + lm) * 512 + t * 128 + ks2 * 32 + lq * 8];
            acc2[i2][j2] = MFMA16(af2, bf2v, acc2[i2][j2], 0, 0, 0);
          }
        }
      }
    }
    __syncthreads();
  }

  if (half == 0) {
    float s = topo_acc + __shfl_xor(topo_acc, 1);
    if ((tid & 1) == 0) {
      const int m = bm * 128 + (tid >> 1);
      a.out[(size_t)m * 69] = s + a.tb2[0];
    }
  } else {
#pragma unroll
    for (int i2 = 0; i2 < 2; ++i2)
#pragma unroll
      for (int j2 = 0; j2 < 4; ++j2)
#pragma unroll
        for (int r = 0; r < 4; ++r) {
          const int m = bm * 128 + wave * 32 + i2 * 16 + lq * 4 + r;
          const int o = j2 * 16 + lm;
          a.out[(size_t)m * 69 + 1 + o] = acc2[i2][j2][r] + a.ab2[o];
        }
  }
}

// ---------------- bond head from materialized hb [M][512] -----------------------
__global__ __launch_bounds__(256) void bond_head(const u16* hb, const float* bw2,
                                                 const float* bb2, float* out) {
  __shared__ u16 hbuf[128 * 136];
  const int tid = threadIdx.x;
  const int bm = blockIdx.x;
  const int srw = tid >> 1, sh = tid & 1;
  float s[4] = {0.f, 0.f, 0.f, 0.f};

  for (int t = 0; t < 4; ++t) {
#pragma unroll
    for (int it = 0; it < 8; ++it) {
      const int id = it * 256 + tid;
      const int row = id >> 4, c8 = (id & 15) * 8;
      short8 v = *(const short8*)(hb + (size_t)(bm * 128 + row) * 512 + t * 128 + c8);
      *(short8*)&hbuf[row * 136 + c8] = v;
    }
    __syncthreads();
    const u16* hrow = &hbuf[srw * 136 + sh * 64];
    for (int cc = 0; cc < 64; ++cc) {
      const float h = bf2f(hrow[cc]);
#pragma unroll
      for (int o = 0; o < 4; ++o)
        s[o] += h * bw2[(t * 128 + sh * 64 + cc) * 4 + o];
    }
    __syncthreads();
  }
#pragma unroll
  for (int o = 0; o < 4; ++o) s[o] += __shfl_xor(s[o], 1);
  if ((tid & 1) == 0) {
    const int m = bm * 128 + srw;
#pragma unroll
    for (int o = 0; o < 4; ++o)
      out[(size_t)m * 69 + 65 + o] = s[o] + bb2[o];
  }
}

// -------- weight transpose + fp32->bf16, LDS-tiled (coalesced both sides) -------
__global__ __launch_bounds__(256) void prep(
    const float* topo_w1, const float* atom_w1, const float* bond_w1,
    const float* rbond_w, const float* wbond_w, const float* atom_w2,
    const float* topo_b1, const float* atom_b1,
    u16* WbT, u16* RbT, u16* TAT, u16* BdT, u16* AT2, float* biasTA) {
  __shared__ float tile[32][33];
  int b = blockIdx.x;
  const float* src; u16* dst; int sld, dld;
  if (b < 256)              { src = wbond_w; dst = WbT; sld = 512; dld = 512; }
  else if ((b -= 256) < 288){ src = rbond_w; dst = RbT; sld = 512; dld = 576; }
  else if ((b -= 288) < 576){ src = topo_w1; dst = TAT; sld = 512; dld = 1152; }
  else if ((b -= 576) < 576){ src = atom_w1; dst = TAT + (size_t)512 * 1152; sld = 512; dld = 1152; }
  else if ((b -= 576) < 832){ src = bond_w1; dst = BdT; sld = 512; dld = 1664; }
  else if ((b -= 832) < 32) { src = atom_w2; dst = AT2; sld = 64;  dld = 512; }
  else {
    for (int i = threadIdx.x; i < 1024; i += 256)
      biasTA[i] = (i < 512) ? topo_b1[i] : atom_b1[i - 512];
    return;
  }
  const int ntn = sld >> 5;
  const int tk = b / ntn, tn = b % ntn;   // tile coords: k (src rows), n (src cols)
  const int t = threadIdx.x;
  const int r = t >> 3, c4 = (t & 7) * 4;
  // coalesced read: 32 rows x 32 cols of src[k][n]
  f32x4 v = *(const f32x4*)&src[(size_t)(tk * 32 + r) * sld + tn * 32 + c4];
#pragma unroll
  for (int j = 0; j < 4; ++j) tile[r][c4 + j] = v[j];
  __syncthreads();
  // coalesced write: dst[n][k] = src[k][n]
  bf16x4 o;
#pragma unroll
  for (int j = 0; j < 4; ++j) o[j] = (short)f2bf(tile[c4 + j][r]);
  *(bf16x4*)&dst[(size_t)(tn * 32 + r) * dld + tk * 32 + c4] = o;
}

extern "C" void kernel_launch(void* const* d_in, const int* in_sizes, int n_in,
                              void* d_out, int out_size, void* d_ws, size_t ws_size,
                              hipStream_t stream) {
  const float* src     = (const float*)d_in[0];
  const float* gvec    = (const float*)d_in[1];
  const float* xnode   = (const float*)d_in[2];
  const float* znode   = (const float*)d_in[3];
  const float* atom1h  = (const float*)d_in[4];
  const float* bond1h  = (const float*)d_in[5];
  const float* topo_w1 = (const float*)d_in[6];
  const float* topo_b1 = (const float*)d_in[7];
  const float* topo_w2 = (const float*)d_in[8];
  const float* topo_b2 = (const float*)d_in[9];
  const float* atom_w1 = (const float*)d_in[10];
  const float* atom_b1 = (const float*)d_in[11];
  const float* atom_w2 = (const float*)d_in[12];
  const float* atom_b2 = (const float*)d_in[13];
  const float* bond_w1 = (const float*)d_in[14];
  const float* bond_b1 = (const float*)d_in[15];
  const float* bond_w2 = (const float*)d_in[16];
  const float* bond_b2 = (const float*)d_in[17];
  const float* rbond_w = (const float*)d_in[18];
  const float* rbond_b = (const float*)d_in[19];
  const float* wbond_w = (const float*)d_in[20];
  const float* wbond_b = (const float*)d_in[21];
  const int* bidx      = (const int*)d_in[22];

  char* ws = (char*)d_ws;
  u16*  WbT    = (u16*)(ws + 0);          // 512x512 bf16
  u16*  RbT    = (u16*)(ws + 524288);     // 512x576
  u16*  TAT    = (u16*)(ws + 1114112);    // 1024x1152
  u16*  BdT    = (u16*)(ws + 3473408);    // 512x1664
  u16*  AT2    = (u16*)(ws + 5177344);    // 64x512
  float* biasTA= (float*)(ws + 5242880);  // [1024] fp32  (end 5246976)
  u16*  gvecB  = (u16*)(ws + 5246976);    // M x 512 bf16 (end 38801408)
  u16*  xnodeB = (u16*)(ws + 38801408);   // M x 512      (end 72355840)
  u16*  ctxB   = (u16*)(ws + 72355840);   // M x 128      (end 80744448)
  u16*  a1hB   = (u16*)(ws + 80744448);   // M x 64       (end 84938752)
  u16*  znodeB = (u16*)(ws + 84938752);   // M x 512      (end 118493184)
  u16*  hist   = (u16*)(ws + 118493184);  // M x 512      (end 152047616)
  u16*  cur    = (u16*)(ws + 152047616);  // M x 512      (end 185602048)
  u16*  hb     = hist;                    // alias: hist dead after g2
  u16*  h1     = znodeB;                  // alias 64MB over znodeB+hist:
                                          // both dead once bond_gemm+bond_head done

  prep<<<dim3(2561), dim3(256), 0, stream>>>(
      topo_w1, atom_w1, bond_w1, rbond_w, wbond_w, atom_w2, topo_b1, atom_b1,
      WbT, RbT, TAT, BdT, AT2, biasTA);

  pack<<<dim3(27648), dim3(256), 0, stream>>>(
      gvec, xnode, znode, src, atom1h, bidx,
      gvecB, xnodeB, znodeB, ctxB, a1hB);

  // g1: hist = relu(znode @ wbond_w[:512] + bond1h @ wbond_w[512:] + b)
  GArgs g1 = {};
  g1.seg[0] = {znodeB, 512, 0}; g1.nseg = 1;
  g1.bt = WbT; g1.biasf = wbond_b; g1.out = hist; g1.K = 512; g1.N = 512;
  g1.tail_w = wbond_w + 512 * 512; g1.tail_x = bond1h;
  gemm256<<<dim3(2, 128), dim3(512), 0, stream>>>(g1);

  // g2: cur = relu([hist ; atom1h] @ rbond_w + b)
  GArgs g2 = {};
  g2.seg[0] = {hist, 512, 0}; g2.seg[1] = {a1hB, 64, 512}; g2.nseg = 2;
  g2.bt = RbT; g2.biasf = rbond_b; g2.out = cur; g2.K = 576; g2.N = 512;
  gemm256<<<dim3(2, 128), dim3(512), 0, stream>>>(g2);

  // bond layer-1: hb = relu([gvec ; cur ; znode ; ctx] @ bond_w1 + b1)
  GArgs gb = {};
  gb.seg[0] = {gvecB, 512, 0}; gb.seg[1] = {cur, 512, 512};
  gb.seg[2] = {znodeB, 512, 1024}; gb.seg[3] = {ctxB, 128, 1536}; gb.nseg = 4;
  gb.bt = BdT; gb.biasf = bond_b1; gb.out = hb; gb.K = 1664; gb.N = 512;
  gemm256<<<dim3(2, 128), dim3(512), 0, stream>>>(gb);

  // bond head (must finish before h1 overwrites hb region)
  bond_head<<<dim3(256), dim3(256), 0, stream>>>(hb, bond_w2, bond_b2, (float*)d_out);

  // ta layer-1: h1 = relu([gvec ; xnode ; ctx] @ [topo_w1|atom_w1] + bias)
  GArgs gt = {};
  gt.seg[0] = {gvecB, 512, 0}; gt.seg[1] = {xnodeB, 512, 512};
  gt.seg[2] = {ctxB, 128, 1024}; gt.nseg = 3;
  gt.bt = TAT; gt.biasf = biasTA; gt.out = h1; gt.K = 1152; gt.N = 1024;
  gemm256<<<dim3(4, 128), dim3(512), 0, stream>>>(gt);

  // topo + atom heads
  THArgs th = {h1, topo_w2, topo_b2, AT2, atom_b2, (float*)d_out};
  ta_heads<<<dim3(2, 256), dim3(256), 0, stream>>>(th);
}

// Round 6
// 522.566 us; speedup vs baseline: 1.1313x; 1.1313x over previous
//
#include <hip/hip_runtime.h>

typedef unsigned short u16;
typedef unsigned int u32;
typedef __attribute__((ext_vector_type(8))) short short8;
typedef __attribute__((ext_vector_type(4))) short bf16x4;
typedef __attribute__((ext_vector_type(4))) float f32x4;

#define M_ROWS 32768
#define MFMA16 __builtin_amdgcn_mfma_f32_16x16x32_bf16

__device__ __forceinline__ float bf2f(u16 u) {
  u32 x = ((u32)u) << 16;
  return __builtin_bit_cast(float, x);
}
__device__ __forceinline__ u16 f2bf(float f) {
  u32 x = __builtin_bit_cast(u32, f);
  x += 0x7fffu + ((x >> 16) & 1u);
  return (u16)(x >> 16);
}
// load 8 fp32 from p, RNE-round to one short8
__device__ __forceinline__ short8 ld8f(const float* p) {
  f32x4 x0 = *(const f32x4*)p;
  f32x4 x1 = *(const f32x4*)(p + 4);
  short8 s;
#pragma unroll
  for (int i = 0; i < 4; ++i) { s[i] = (short)f2bf(x0[i]); s[4 + i] = (short)f2bf(x1[i]); }
  return s;
}

// async global->LDS, 16B per lane, LDS dest = wave-uniform base + lane*16
__device__ __forceinline__ void lds16(u16* l, const u16* g) {
  __builtin_amdgcn_global_load_lds(
      (const __attribute__((address_space(1))) void*)g,
      (__attribute__((address_space(3))) void*)l, 16, 0, 0);
}

#define ASM_VMCNT4 asm volatile("s_waitcnt vmcnt(4)" ::: "memory")
#define ASM_VMCNT0 asm volatile("s_waitcnt vmcnt(0)" ::: "memory")
#define BAR asm volatile("s_barrier" ::: "memory")
#define LGKM0 do { asm volatile("s_waitcnt lgkmcnt(0)" ::: "memory"); \
                   __builtin_amdgcn_sched_barrier(0); } while (0)

// ---------------- input pack: fp32 -> bf16 (+ ctx gather) -----------------------
__global__ __launch_bounds__(256) void pack(
    const float* gvec, const float* xnode, const float* znode,
    const float* src, const float* atom1h, const int* bidx,
    u16* gvecB, u16* xnodeB, u16* znodeB, u16* ctxB, u16* a1hB) {
  int id = blockIdx.x * 256 + threadIdx.x;  // one short8 chunk each
  const int NG = M_ROWS * 512 / 8;          // 2097152
  if (id < NG) { ((short8*)gvecB)[id] = ld8f(gvec + (size_t)id * 8); return; }
  id -= NG;
  if (id < NG) { ((short8*)xnodeB)[id] = ld8f(xnode + (size_t)id * 8); return; }
  id -= NG;
  if (id < NG) { ((short8*)znodeB)[id] = ld8f(znode + (size_t)id * 8); return; }
  id -= NG;
  const int NC = M_ROWS * 128 / 8;          // 524288
  if (id < NC) {
    const int m = id >> 4, c8 = (id & 15) * 8;
    ((short8*)ctxB)[id] = ld8f(src + (size_t)bidx[m] * 128 + c8);
    return;
  }
  id -= NC;
  const int NA = M_ROWS * 64 / 8;           // 262144
  if (id < NA) { ((short8*)a1hB)[id] = ld8f(atom1h + (size_t)id * 8); return; }
}

// ---- 256x256 GEMM, 4-phase K-tile pipeline, counted vmcnt (T2+T3+T4+T5) --------
// out = relu(A @ B^T + bias [+ tail rank-4]) in bf16
struct SegB { const u16* ptr; int ld; int kstart; };
struct GArgs {
  SegB seg[4];
  int nseg;
  const u16* bt;       // B^T [N][K] bf16
  const float* biasf;  // [N] fp32
  u16* out;            // [M][N] relu'd bf16
  int K;
  int N;
  const float* tail_w; // fp32 wbond_w rows 512..515 (ld 512) or null
  const float* tail_x; // fp32 bond_onehot [M][4] or null
};

__global__ __launch_bounds__(512) void gemm256(GArgs a) {
  // [buf][ks-half][256 rows][32 cols] bf16: A 64 KB + B 64 KB = 128 KB
  __shared__ __align__(16) u16 Ab[2 * 16384];
  __shared__ __align__(16) u16 Bb[2 * 16384];
  const int tid = threadIdx.x;
  // bijective XCD-chunked swizzle (nwg % 8 == 0 in all launches)
  const int nwg = gridDim.x * gridDim.y;
  const int orig = blockIdx.y * gridDim.x + blockIdx.x;
  const int swz = (orig & 7) * (nwg >> 3) + (orig >> 3);
  const int bn = swz % gridDim.x, bm = swz / gridDim.x;
  const int wave = tid >> 6, lane = tid & 63;
  const int wm = wave >> 2, wn = wave & 3;   // 2M x 4N wave grid
  const int lm = lane & 15, lq = lane >> 4;
  // staging: per half-tile 2 loads/thread; row = j*128 + (tid>>2)
  const int srow = tid >> 2;                              // 0..127
  const int scol = ((tid & 3) ^ ((tid >> 3) & 3)) * 8;    // pre-swizzled src col
  // frag read col (xor-swizzled 16B slot within 32-col row)
  const int cxe = (lq ^ ((lm >> 1) & 3)) * 8;
  const int K = a.K;
  const int nt = K >> 6;                                  // # 64-K tiles
  const u16* bpan = a.bt + (size_t)(bn * 256) * K;
  const int aRow = wm * 128 + lm;   // A frag base row
  const int bRow = wn * 64 + lm;    // B frag base row
  f32x4 acc[8][4] = {};

  // stage one 256x32 half: A variant (segment lookup) ---------------------------
  auto stageA = [&](int kb, u16* dst) {
    int si = a.nseg - 1;
    while (si > 0 && kb < a.seg[si].kstart) --si;
    const int ld = a.seg[si].ld;
    const u16* ap = a.seg[si].ptr + (size_t)(bm * 256) * ld + (kb - a.seg[si].kstart) + scol;
    lds16(dst + tid * 8,        ap + (size_t)srow * ld);
    lds16(dst + 4096 + tid * 8, ap + (size_t)(128 + srow) * ld);
  };
  auto stageB = [&](int kb, u16* dst) {
    const u16* bp = bpan + kb + scol;
    lds16(dst + tid * 8,        bp + (size_t)srow * K);
    lds16(dst + 4096 + tid * 8, bp + (size_t)(128 + srow) * K);
  };

  // prologue: tile 0 halves in order A-K0, B-K0, A-K1, B-K1 (8 loads)
  stageA(0, Ab);           // A-K0 -> buf0 ks0
  stageB(0, Bb);           // B-K0
  stageA(32, Ab + 8192);   // A-K1
  stageB(32, Bb + 8192);   // B-K1
  ASM_VMCNT4;              // A-K0 + B-K0 landed
  BAR;

  for (int t = 0; t < nt; ++t) {
    const u16* Ac = Ab + (t & 1) * 16384;
    const u16* Bc = Bb + (t & 1) * 16384;
    u16* An = Ab + ((t + 1) & 1) * 16384;
    u16* Bn = Bb + ((t + 1) & 1) * 16384;
    const bool pf = (t + 1 < nt);
    const int kb1 = (t + 1) << 6;
    short8 afr[8], blo[2], bhi[2];

    // ---- P1: read A-ks0 (8) + B-nlo-ks0 (2) | stage A-K0(t+1) | MFMA n0-1 ks0
#pragma unroll
    for (int m = 0; m < 8; ++m)
      afr[m] = *(const short8*)&Ac[(aRow + m * 16) * 32 + cxe];
#pragma unroll
    for (int n = 0; n < 2; ++n)
      blo[n] = *(const short8*)&Bc[(bRow + n * 16) * 32 + cxe];
    if (pf) stageA(kb1, An);
    BAR;
    LGKM0;
    __builtin_amdgcn_s_setprio(1);
#pragma unroll
    for (int m = 0; m < 8; ++m)
#pragma unroll
      for (int n = 0; n < 2; ++n)
        acc[m][n] = MFMA16(afr[m], blo[n], acc[m][n], 0, 0, 0);
    __builtin_amdgcn_s_setprio(0);

    // ---- P2: read B-nhi-ks0 (2) | stage B-K0(t+1) | vmcnt(4) | MFMA n2-3 ks0
#pragma unroll
    for (int n = 0; n < 2; ++n)
      bhi[n] = *(const short8*)&Bc[(bRow + (2 + n) * 16) * 32 + cxe];
    if (pf) { stageB(kb1, Bn); ASM_VMCNT4; } else { ASM_VMCNT0; }
    BAR;
    LGKM0;
    __builtin_amdgcn_s_setprio(1);
#pragma unroll
    for (int m = 0; m < 8; ++m)
#pragma unroll
      for (int n = 0; n < 2; ++n)
        acc[m][2 + n] = MFMA16(afr[m], bhi[n], acc[m][2 + n], 0, 0, 0);
    __builtin_amdgcn_s_setprio(0);

    // ---- P3: read A-ks1 (8) + B-nlo-ks1 (2) | stage A-K1(t+1) | MFMA n0-1 ks1
#pragma unroll
    for (int m = 0; m < 8; ++m)
      afr[m] = *(const short8*)&Ac[8192 + (aRow + m * 16) * 32 + cxe];
#pragma unroll
    for (int n = 0; n < 2; ++n)
      blo[n] = *(const short8*)&Bc[8192 + (bRow + n * 16) * 32 + cxe];
    if (pf) stageA(kb1 + 32, An + 8192);
    BAR;
    LGKM0;
    __builtin_amdgcn_s_setprio(1);
#pragma unroll
    for (int m = 0; m < 8; ++m)
#pragma unroll
      for (int n = 0; n < 2; ++n)
        acc[m][n] = MFMA16(afr[m], blo[n], acc[m][n], 0, 0, 0);
    __builtin_amdgcn_s_setprio(0);

    // ---- P4: read B-nhi-ks1 (2) | stage B-K1(t+1) | vmcnt(4) | MFMA n2-3 ks1
#pragma unroll
    for (int n = 0; n < 2; ++n)
      bhi[n] = *(const short8*)&Bc[8192 + (bRow + (2 + n) * 16) * 32 + cxe];
    if (pf) { stageB(kb1 + 32, Bn + 8192); ASM_VMCNT4; }
    BAR;
    LGKM0;
    __builtin_amdgcn_s_setprio(1);
#pragma unroll
    for (int m = 0; m < 8; ++m)
#pragma unroll
      for (int n = 0; n < 2; ++n)
        acc[m][2 + n] = MFMA16(afr[m], bhi[n], acc[m][2 + n], 0, 0, 0);
    __builtin_amdgcn_s_setprio(0);
  }

  // ---- epilogue: bias [+rank-4 tail] + relu + bf16 store ----
  const int gc0 = bn * 256 + wn * 64 + lm;
  float biasv[4], tw[4][4];
#pragma unroll
  for (int j = 0; j < 4; ++j) {
    biasv[j] = a.biasf[gc0 + j * 16];
    if (a.tail_w) {
#pragma unroll
      for (int o = 0; o < 4; ++o) tw[j][o] = a.tail_w[o * 512 + gc0 + j * 16];
    }
  }
#pragma unroll
  for (int i = 0; i < 8; ++i) {
#pragma unroll
    for (int r = 0; r < 4; ++r) {
      const int gr = bm * 256 + wm * 128 + i * 16 + lq * 4 + r;
      float tx0 = 0.f, tx1 = 0.f, tx2 = 0.f, tx3 = 0.f;
      if (a.tail_w) {
        f32x4 t = *(const f32x4*)&a.tail_x[gr * 4];
        tx0 = t[0]; tx1 = t[1]; tx2 = t[2]; tx3 = t[3];
      }
#pragma unroll
      for (int j = 0; j < 4; ++j) {
        float v = acc[i][j][r] + biasv[j];
        if (a.tail_w) v += tx0 * tw[j][0] + tx1 * tw[j][1] + tx2 * tw[j][2] + tx3 * tw[j][3];
        v = v > 0.f ? v : 0.f;
        a.out[(size_t)gr * a.N + gc0 + j * 16] = f2bf(v);
      }
    }
  }
}

// ---------------- topo + atom heads from materialized h1 [M][1024] --------------
struct THArgs {
  const u16* h1;      // [M][1024] relu'd bf16 (cols 0..511 topo, 512..1023 atom)
  const float* tw2;   // topo_w2 [512] fp32
  const float* tb2;   // topo_b2 [1]
  const u16* aw2t;    // AT2 [64][512] bf16
  const float* ab2;   // atom_b2 [64]
  float* out;         // [M][69] fp32
};

__global__ __launch_bounds__(256) void ta_heads(THArgs a) {
  __shared__ u16 hbuf[128 * 136];
  const int tid = threadIdx.x;
  const int half = blockIdx.x, bm = blockIdx.y;  // half: 0=topo, 1=atom
  const int wave = tid >> 6, lane = tid & 63;
  const int lm = lane & 15, lq = lane >> 4;

  float topo_acc = 0.f;
  f32x4 acc2[2][4] = {};

  for (int t = 0; t < 4; ++t) {
    // stage h1[bm*128 ..][half*512 + t*128 ..] -> hbuf[128][136] (padded)
#pragma unroll
    for (int it = 0; it < 8; ++it) {
      const int id = it * 256 + tid;
      const int row = id >> 4, c8 = (id & 15) * 8;
      short8 v = *(const short8*)(a.h1 + (size_t)(bm * 128 + row) * 1024 + half * 512 + t * 128 + c8);
      *(short8*)&hbuf[row * 136 + c8] = v;
    }
    __syncthreads();

    if (half == 0) {
      const int srw = tid >> 1, sh = tid & 1;
      const u16* hrow = &hbuf[srw * 136 + sh * 64];
      float s = 0.f;
      for (int cc = 0; cc < 64; ++cc)
        s += bf2f(hrow[cc]) * a.tw2[t * 128 + sh * 64 + cc];
      topo_acc += s;
    } else {
#pragma unroll
      for (int ks2 = 0; ks2 < 4; ++ks2) {
#pragma unroll
        for (int i2 = 0; i2 < 2; ++i2) {
          const short8 af2 = *(const short8*)&hbuf[(wave * 32 + i2 * 16 + lm) * 136 + ks2 * 32 + lq * 8];
#pragma unroll
          for (int j2 = 0; j2 < 4; ++j2) {
            const short8 bf2v = *(const short8*)&a.aw2t[(size_t)(j2 * 16 + lm) * 512 + t * 128 + ks2 * 32 + lq * 8];
            acc2[i2][j2] = MFMA16(af2, bf2v, acc2[i2][j2], 0, 0, 0);
          }
        }
      }
    }
    __syncthreads();
  }

  if (half == 0) {
    float s = topo_acc + __shfl_xor(topo_acc, 1);
    if ((tid & 1) == 0) {
      const int m = bm * 128 + (tid >> 1);
      a.out[(size_t)m * 69] = s + a.tb2[0];
    }
  } else {
#pragma unroll
    for (int i2 = 0; i2 < 2; ++i2)
#pragma unroll
      for (int j2 = 0; j2 < 4; ++j2)
#pragma unroll
        for (int r = 0; r < 4; ++r) {
          const int m = bm * 128 + wave * 32 + i2 * 16 + lq * 4 + r;
          const int o = j2 * 16 + lm;
          a.out[(size_t)m * 69 + 1 + o] = acc2[i2][j2][r] + a.ab2[o];
        }
  }
}

// ---------------- bond head from materialized hb [M][512] -----------------------
__global__ __launch_bounds__(256) void bond_head(const u16* hb, const float* bw2,
                                                 const float* bb2, float* out) {
  __shared__ u16 hbuf[128 * 136];
  const int tid = threadIdx.x;
  const int bm = blockIdx.x;
  const int srw = tid >> 1, sh = tid & 1;
  float s[4] = {0.f, 0.f, 0.f, 0.f};

  for (int t = 0; t < 4; ++t) {
#pragma unroll
    for (int it = 0; it < 8; ++it) {
      const int id = it * 256 + tid;
      const int row = id >> 4, c8 = (id & 15) * 8;
      short8 v = *(const short8*)(hb + (size_t)(bm * 128 + row) * 512 + t * 128 + c8);
      *(short8*)&hbuf[row * 136 + c8] = v;
    }
    __syncthreads();
    const u16* hrow = &hbuf[srw * 136 + sh * 64];
    for (int cc = 0; cc < 64; ++cc) {
      const float h = bf2f(hrow[cc]);
#pragma unroll
      for (int o = 0; o < 4; ++o)
        s[o] += h * bw2[(t * 128 + sh * 64 + cc) * 4 + o];
    }
    __syncthreads();
  }
#pragma unroll
  for (int o = 0; o < 4; ++o) s[o] += __shfl_xor(s[o], 1);
  if ((tid & 1) == 0) {
    const int m = bm * 128 + srw;
#pragma unroll
    for (int o = 0; o < 4; ++o)
      out[(size_t)m * 69 + 65 + o] = s[o] + bb2[o];
  }
}

// -------- weight transpose + fp32->bf16, LDS-tiled (coalesced both sides) -------
__global__ __launch_bounds__(256) void prep(
    const float* topo_w1, const float* atom_w1, const float* bond_w1,
    const float* rbond_w, const float* wbond_w, const float* atom_w2,
    const float* topo_b1, const float* atom_b1,
    u16* WbT, u16* RbT, u16* TAT, u16* BdT, u16* AT2, float* biasTA) {
  __shared__ float tile[32][33];
  int b = blockIdx.x;
  const float* src; u16* dst; int sld, dld;
  if (b < 256)              { src = wbond_w; dst = WbT; sld = 512; dld = 512; }
  else if ((b -= 256) < 288){ src = rbond_w; dst = RbT; sld = 512; dld = 576; }
  else if ((b -= 288) < 576){ src = topo_w1; dst = TAT; sld = 512; dld = 1152; }
  else if ((b -= 576) < 576){ src = atom_w1; dst = TAT + (size_t)512 * 1152; sld = 512; dld = 1152; }
  else if ((b -= 576) < 832){ src = bond_w1; dst = BdT; sld = 512; dld = 1664; }
  else if ((b -= 832) < 32) { src = atom_w2; dst = AT2; sld = 64;  dld = 512; }
  else {
    for (int i = threadIdx.x; i < 1024; i += 256)
      biasTA[i] = (i < 512) ? topo_b1[i] : atom_b1[i - 512];
    return;
  }
  const int ntn = sld >> 5;
  const int tk = b / ntn, tn = b % ntn;   // tile coords: k (src rows), n (src cols)
  const int t = threadIdx.x;
  const int r = t >> 3, c4 = (t & 7) * 4;
  // coalesced read: 32 rows x 32 cols of src[k][n]
  f32x4 v = *(const f32x4*)&src[(size_t)(tk * 32 + r) * sld + tn * 32 + c4];
#pragma unroll
  for (int j = 0; j < 4; ++j) tile[r][c4 + j] = v[j];
  __syncthreads();
  // coalesced write: dst[n][k] = src[k][n]
  bf16x4 o;
#pragma unroll
  for (int j = 0; j < 4; ++j) o[j] = (short)f2bf(tile[c4 + j][r]);
  *(bf16x4*)&dst[(size_t)(tn * 32 + r) * dld + tk * 32 + c4] = o;
}

extern "C" void kernel_launch(void* const* d_in, const int* in_sizes, int n_in,
                              void* d_out, int out_size, void* d_ws, size_t ws_size,
                              hipStream_t stream) {
  const float* src     = (const float*)d_in[0];
  const float* gvec    = (const float*)d_in[1];
  const float* xnode   = (const float*)d_in[2];
  const float* znode   = (const float*)d_in[3];
  const float* atom1h  = (const float*)d_in[4];
  const float* bond1h  = (const float*)d_in[5];
  const float* topo_w1 = (const float*)d_in[6];
  const float* topo_b1 = (const float*)d_in[7];
  const float* topo_w2 = (const float*)d_in[8];
  const float* topo_b2 = (const float*)d_in[9];
  const float* atom_w1 = (const float*)d_in[10];
  const float* atom_b1 = (const float*)d_in[11];
  const float* atom_w2 = (const float*)d_in[12];
  const float* atom_b2 = (const float*)d_in[13];
  const float* bond_w1 = (const float*)d_in[14];
  const float* bond_b1 = (const float*)d_in[15];
  const float* bond_w2 = (const float*)d_in[16];
  const float* bond_b2 = (const float*)d_in[17];
  const float* rbond_w = (const float*)d_in[18];
  const float* rbond_b = (const float*)d_in[19];
  const float* wbond_w = (const float*)d_in[20];
  const float* wbond_b = (const float*)d_in[21];
  const int* bidx      = (const int*)d_in[22];

  char* ws = (char*)d_ws;
  u16*  WbT    = (u16*)(ws + 0);          // 512x512 bf16
  u16*  RbT    = (u16*)(ws + 524288);     // 512x576
  u16*  TAT    = (u16*)(ws + 1114112);    // 1024x1152
  u16*  BdT    = (u16*)(ws + 3473408);    // 512x1664
  u16*  AT2    = (u16*)(ws + 5177344);    // 64x512
  float* biasTA= (float*)(ws + 5242880);  // [1024] fp32  (end 5246976)
  u16*  gvecB  = (u16*)(ws + 5246976);    // M x 512 bf16 (end 38801408)
  u16*  xnodeB = (u16*)(ws + 38801408);   // M x 512      (end 72355840)
  u16*  ctxB   = (u16*)(ws + 72355840);   // M x 128      (end 80744448)
  u16*  a1hB   = (u16*)(ws + 80744448);   // M x 64       (end 84938752)
  u16*  znodeB = (u16*)(ws + 84938752);   // M x 512      (end 118493184)
  u16*  hist   = (u16*)(ws + 118493184);  // M x 512      (end 152047616)
  u16*  cur    = (u16*)(ws + 152047616);  // M x 512      (end 185602048)
  u16*  hb     = hist;                    // alias: hist dead after g2
  u16*  h1     = znodeB;                  // alias 64MB over znodeB+hist:
                                          // both dead once bond_gemm+bond_head done

  prep<<<dim3(2561), dim3(256), 0, stream>>>(
      topo_w1, atom_w1, bond_w1, rbond_w, wbond_w, atom_w2, topo_b1, atom_b1,
      WbT, RbT, TAT, BdT, AT2, biasTA);

  pack<<<dim3(27648), dim3(256), 0, stream>>>(
      gvec, xnode, znode, src, atom1h, bidx,
      gvecB, xnodeB, znodeB, ctxB, a1hB);

  // g1: hist = relu(znode @ wbond_w[:512] + bond1h @ wbond_w[512:] + b)
  GArgs g1 = {};
  g1.seg[0] = {znodeB, 512, 0}; g1.nseg = 1;
  g1.bt = WbT; g1.biasf = wbond_b; g1.out = hist; g1.K = 512; g1.N = 512;
  g1.tail_w = wbond_w + 512 * 512; g1.tail_x = bond1h;
  gemm256<<<dim3(2, 128), dim3(512), 0, stream>>>(g1);

  // g2: cur = relu([hist ; atom1h] @ rbond_w + b)
  GArgs g2 = {};
  g2.seg[0] = {hist, 512, 0}; g2.seg[1] = {a1hB, 64, 512}; g2.nseg = 2;
  g2.bt = RbT; g2.biasf = rbond_b; g2.out = cur; g2.K = 576; g2.N = 512;
  gemm256<<<dim3(2, 128), dim3(512), 0, stream>>>(g2);

  // bond layer-1: hb = relu([gvec ; cur ; znode ; ctx] @ bond_w1 + b1)
  GArgs gb = {};
  gb.seg[0] = {gvecB, 512, 0}; gb.seg[1] = {cur, 512, 512};
  gb.seg[2] = {znodeB, 512, 1024}; gb.seg[3] = {ctxB, 128, 1536}; gb.nseg = 4;
  gb.bt = BdT; gb.biasf = bond_b1; gb.out = hb; gb.K = 1664; gb.N = 512;
  gemm256<<<dim3(2, 128), dim3(512), 0, stream>>>(gb);

  // bond head (must finish before h1 overwrites hb region)
  bond_head<<<dim3(256), dim3(256), 0, stream>>>(hb, bond_w2, bond_b2, (float*)d_out);

  // ta layer-1: h1 = relu([gvec ; xnode ; ctx] @ [topo_w1|atom_w1] + bias)
  GArgs gt = {};
  gt.seg[0] = {gvecB, 512, 0}; gt.seg[1] = {xnodeB, 512, 512};
  gt.seg[2] = {ctxB, 128, 1024}; gt.nseg = 3;
  gt.bt = TAT; gt.biasf = biasTA; gt.out = h1; gt.K = 1152; gt.N = 1024;
  gemm256<<<dim3(4, 128), dim3(512), 0, stream>>>(gt);

  // topo + atom heads
  THArgs th = {h1, topo_w2, topo_b2, AT2, atom_b2, (float*)d_out};
  ta_heads<<<dim3(2, 256), dim3(256), 0, stream>>>(th);
}